// Round 3
// baseline (767.688 us; speedup 1.0000x reference)
//
#include <hip/hip_runtime.h>

// Elman RNN (relu), B=4096 T=4096 H=32, fp32.
// Mapping: 16-lane DPP row = 1 batch; lane j holds hidden units j and j+16.
// h_new[j] = relu( sum_k h[k]*W_hh[j,k] + x*W_ih[j] + b_ih[j]+b_hh[j] )
// Cross-lane h via v_fmac_f32_dpp row_ror:m (lane j reads h[(j-m)&15]),
// weights pre-gathered per lane so the coefficient matches the rotation.
// 1024 waves = 1 wave/SIMD across 256 CUs; 64 fmac/step/wave = the floor.
//
// R1/R2 post-mortem: default allocator budget = 64 arch VGPRs (targets 8
// waves/EU); the 64 weight coeffs spilled to AGPRs -> ~60 v_accvgpr_read +
// 60 hazard s_nops per step (measured 440 cyc/step vs 148 designed).
// __launch_bounds__(256,1) did NOT raise the budget (binary unchanged).
// Fix: native attributes amdgpu_waves_per_eu(1,1) -> budget = 256 arch
// VGPRs, weights stay in arch VGPRs, copies + nops vanish.

#define HSZ 32

// v_fmac_f32_dpp: dst(acc) += src0(dpp-rotated h) * src1(w)
#define FMAC_DPP(acc, src, w, mlit)                                           \
  asm("v_fmac_f32_dpp %0, %1, %2 row_ror:" mlit " row_mask:0xf bank_mask:0xf" \
      : "+v"(acc)                                                             \
      : "v"(src), "v"(w))

#define STEP_M(mi, mlit)             \
  FMAC_DPP(aA, h_lo, wll[mi], mlit); \
  FMAC_DPP(aB, h_hi, wlh[mi], mlit); \
  FMAC_DPP(aC, h_lo, whl[mi], mlit); \
  FMAC_DPP(aD, h_hi, whh[mi], mlit)

// One recurrence step. Reads h_lo/h_hi (prev), writes them (new).
// relu via asm ending in s_nop 1: gfx9 "VALU write -> DPP read" hazard needs
// 2 wait states; keep it explicit since the compiler can't see into the
// downstream DPP asm. (Proven correct in R1/R2; costs ~4 cyc/step.)
#define RNN_STEP(xs)                                                   \
  do {                                                                 \
    float aA = fmaf((xs), wih_lo, c_lo); /* xin_lo */                  \
    float aC = fmaf((xs), wih_hi, c_hi); /* xin_hi */                  \
    float aB = h_hi * wlh[0];                                          \
    float aD = h_hi * whh[0];                                          \
    aA = fmaf(h_lo, wll[0], aA);                                       \
    aC = fmaf(h_lo, whl[0], aC);                                       \
    STEP_M(1, "1");   STEP_M(2, "2");   STEP_M(3, "3");                \
    STEP_M(4, "4");   STEP_M(5, "5");   STEP_M(6, "6");                \
    STEP_M(7, "7");   STEP_M(8, "8");   STEP_M(9, "9");                \
    STEP_M(10, "10"); STEP_M(11, "11"); STEP_M(12, "12");              \
    STEP_M(13, "13"); STEP_M(14, "14"); STEP_M(15, "15");              \
    float slo = aA + aB;                                               \
    float shi = aC + aD;                                               \
    asm("v_max_f32 %0, 0, %1\n\ts_nop 1" : "=v"(h_lo) : "v"(slo));     \
    asm("v_max_f32 %0, 0, %1\n\ts_nop 1" : "=v"(h_hi) : "v"(shi));     \
  } while (0)

__global__ __attribute__((amdgpu_flat_work_group_size(256, 256),
                          amdgpu_waves_per_eu(1, 1)))
void rnn_reg_kernel(
    const float* __restrict__ x, const float* __restrict__ h_init,
    const float* __restrict__ W_ih, const float* __restrict__ W_hh,
    const float* __restrict__ b_ih, const float* __restrict__ b_hh,
    const float* __restrict__ W_reg, const float* __restrict__ b_reg,
    float* __restrict__ out, int T) {
  const int jj  = threadIdx.x & 15;   // hidden-lane within row
  const int row = threadIdx.x >> 4;   // 0..15 rows per block
  const int b   = blockIdx.x * 16 + row;

  // Per-lane gathered W_hh so that with row_ror:m (lane j sees h[(j-m)&15])
  // the coefficient is W_hh[out_row, in_col=(j-m)&15].
  float wll[16], wlh[16], whl[16], whh[16];
#pragma unroll
  for (int m = 0; m < 16; ++m) {
    int k = (jj - m) & 15;
    wll[m] = W_hh[jj * HSZ + k];              // out j,    in k
    wlh[m] = W_hh[jj * HSZ + 16 + k];         // out j,    in 16+k
    whl[m] = W_hh[(jj + 16) * HSZ + k];       // out j+16, in k
    whh[m] = W_hh[(jj + 16) * HSZ + 16 + k];  // out j+16, in 16+k
  }
  const float wih_lo = W_ih[jj];
  const float wih_hi = W_ih[jj + 16];
  const float c_lo = b_ih[jj] + b_hh[jj];
  const float c_hi = b_ih[jj + 16] + b_hh[jj + 16];

  float h_lo = h_init[b * HSZ + jj];
  float h_hi = h_init[b * HSZ + jj + 16];

  // x feed: all 16 lanes of a row load the same float4 (HW merges the
  // same-address lanes). 4-deep rotating pipeline = 16-step prefetch
  // distance (~2300 cyc) covering cold-HBM latency (~900 cyc).
  const float4* xv = (const float4*)(x + (size_t)b * (size_t)T);
  const int last = T / 4 - 1;
  float4 x0 = xv[0], x1 = xv[1], x2 = xv[2], x3 = xv[3];

#pragma unroll 1
  for (int t = 0; t < T; t += 16) {
    const int base = t >> 2;
    int i0 = base + 4; i0 = i0 > last ? last : i0;
    int i1 = base + 5; i1 = i1 > last ? last : i1;
    int i2 = base + 6; i2 = i2 > last ? last : i2;
    int i3 = base + 7; i3 = i3 > last ? last : i3;
    float4 n0 = xv[i0];
    RNN_STEP(x0.x); RNN_STEP(x0.y); RNN_STEP(x0.z); RNN_STEP(x0.w);
    float4 n1 = xv[i1];
    RNN_STEP(x1.x); RNN_STEP(x1.y); RNN_STEP(x1.z); RNN_STEP(x1.w);
    float4 n2 = xv[i2];
    RNN_STEP(x2.x); RNN_STEP(x2.y); RNN_STEP(x2.z); RNN_STEP(x2.w);
    float4 n3 = xv[i3];
    RNN_STEP(x3.x); RNN_STEP(x3.y); RNN_STEP(x3.z); RNN_STEP(x3.w);
    x0 = n0; x1 = n1; x2 = n2; x3 = n3;
  }

  // out[b] = sum_j h[j]*W_reg[j] + b_reg  (reduce across the 16-lane row)
  const float wr_lo = W_reg[jj];
  const float wr_hi = W_reg[jj + 16];
  float v = fmaf(h_lo, wr_lo, h_hi * wr_hi);
  v += __shfl_xor(v, 1, 16);
  v += __shfl_xor(v, 2, 16);
  v += __shfl_xor(v, 4, 16);
  v += __shfl_xor(v, 8, 16);
  if (jj == 0) out[b] = v + b_reg[0];
}

extern "C" void kernel_launch(void* const* d_in, const int* in_sizes, int n_in,
                              void* d_out, int out_size, void* d_ws, size_t ws_size,
                              hipStream_t stream) {
  const float* x      = (const float*)d_in[0];
  const float* h_init = (const float*)d_in[1];
  const float* W_ih   = (const float*)d_in[2];
  const float* W_hh   = (const float*)d_in[3];
  const float* b_ih   = (const float*)d_in[4];
  const float* b_hh   = (const float*)d_in[5];
  const float* W_reg  = (const float*)d_in[6];
  const float* b_reg  = (const float*)d_in[7];
  float* out = (float*)d_out;

  const int B = in_sizes[1] / HSZ;          // 4096
  const int T = in_sizes[0] / B;            // 4096
  const int grid = B / 16;                  // 16 batches (rows) per 256-thr block

  rnn_reg_kernel<<<dim3(grid), dim3(256), 0, stream>>>(
      x, h_init, W_ih, W_hh, b_ih, b_hh, W_reg, b_reg, out, T);
}

// Round 4
// 724.066 us; speedup vs baseline: 1.0602x; 1.0602x over previous
//
#include <hip/hip_runtime.h>

// Elman RNN (relu), B=4096 T=4096 H=32, fp32.
// Mapping: 16-lane DPP row = 1 batch; lane j holds hidden units j and j+16.
// h_new[j] = relu( sum_k h[k]*W_hh[j,k] + x*W_ih[j] + b_ih[j]+b_hh[j] )
// Cross-lane h via v_fmac_f32_dpp row_ror:m (lane j reads h[(j-m)&15]),
// weights pre-gathered per lane so the coefficient matches the rotation.
// 1024 waves = 1 wave/SIMD across 256 CUs; 64 fmac/step/wave = the floor.
//
// R3 post-mortem: R1(AGPR codegen) == R3(clean VGPR codegen) at 433 cyc/step
// -> latency-bound, not issue-bound. Non-volatile asm let the scheduler group
// each accumulator's 16 dependent DPP-fmacs back-to-back; 433/64 = 6.8 cyc
// per dependent DPP link (VALUBusy 68% = 64*4.6/433 consistent).
// Fix: (a) asm volatile pins program order (volatile asms are not reordered
// w.r.t. each other); (b) 8 accumulator chains (m 0..7 / 8..15 per matrix
// quadrant), interleaved 8-wide -> dependent spacing 16 cyc >> ~7 cyc latency.

#define HSZ 32

// acc += dpp_row_ror<m>(src) * w
#define FMAC_DPP(acc, src, w, mlit)                                           \
  asm volatile(                                                               \
      "v_fmac_f32_dpp %0, %1, %2 row_ror:" mlit " row_mask:0xf bank_mask:0xf" \
      : "+v"(acc)                                                             \
      : "v"(src), "v"(w))

// dst = dpp_row_ror<m>(src) * w   (chain-1 initializer)
#define MUL_DPP(dst, src, w, mlit)                                            \
  asm volatile(                                                               \
      "v_mul_f32_dpp %0, %1, %2 row_ror:" mlit " row_mask:0xf bank_mask:0xf"  \
      : "=v"(dst)                                                             \
      : "v"(src), "v"(w))

// 8-wide interleave: chain-0 ops at rotation m0, chain-1 ops at rotation m1.
// Dependent reuse of any accumulator is 8 instructions (16 cycles) apart.
#define STEP_PAIR(m0i, m0lit, m1i, m1lit)   \
  FMAC_DPP(aA0, h_lo, wll[m0i], m0lit);     \
  FMAC_DPP(aB0, h_hi, wlh[m0i], m0lit);     \
  FMAC_DPP(aC0, h_lo, whl[m0i], m0lit);     \
  FMAC_DPP(aD0, h_hi, whh[m0i], m0lit);     \
  FMAC_DPP(aA1, h_lo, wll[m1i], m1lit);     \
  FMAC_DPP(aB1, h_hi, wlh[m1i], m1lit);     \
  FMAC_DPP(aC1, h_lo, whl[m1i], m1lit);     \
  FMAC_DPP(aD1, h_hi, whh[m1i], m1lit)

// One recurrence step. relu asm ends in s_nop 1: gfx9 "VALU write -> DPP
// read of that reg as src0 needs 2 wait states" — h is every DPP's src0.
#define RNN_STEP(xs)                                                   \
  do {                                                                 \
    float aA0 = fmaf((xs), wih_lo, c_lo);                              \
    float aC0 = fmaf((xs), wih_hi, c_hi);                              \
    aA0 = fmaf(h_lo, wll[0], aA0);                                     \
    aC0 = fmaf(h_lo, whl[0], aC0);                                     \
    float aB0 = h_hi * wlh[0];                                         \
    float aD0 = h_hi * whh[0];                                         \
    float aA1, aB1, aC1, aD1;                                          \
    MUL_DPP(aA1, h_lo, wll[8], "8");                                   \
    MUL_DPP(aB1, h_hi, wlh[8], "8");                                   \
    MUL_DPP(aC1, h_lo, whl[8], "8");                                   \
    MUL_DPP(aD1, h_hi, whh[8], "8");                                   \
    STEP_PAIR(1, "1", 9, "9");                                         \
    STEP_PAIR(2, "2", 10, "10");                                       \
    STEP_PAIR(3, "3", 11, "11");                                       \
    STEP_PAIR(4, "4", 12, "12");                                       \
    STEP_PAIR(5, "5", 13, "13");                                       \
    STEP_PAIR(6, "6", 14, "14");                                       \
    STEP_PAIR(7, "7", 15, "15");                                       \
    float slo = (aA0 + aB0) + (aA1 + aB1);                             \
    float shi = (aC0 + aD0) + (aC1 + aD1);                             \
    asm volatile("v_max_f32 %0, 0, %1\n\ts_nop 1"                      \
                 : "=v"(h_lo) : "v"(slo));                             \
    asm volatile("v_max_f32 %0, 0, %1\n\ts_nop 1"                      \
                 : "=v"(h_hi) : "v"(shi));                             \
  } while (0)

__global__ __attribute__((amdgpu_flat_work_group_size(256, 256),
                          amdgpu_waves_per_eu(1, 1)))
void rnn_reg_kernel(
    const float* __restrict__ x, const float* __restrict__ h_init,
    const float* __restrict__ W_ih, const float* __restrict__ W_hh,
    const float* __restrict__ b_ih, const float* __restrict__ b_hh,
    const float* __restrict__ W_reg, const float* __restrict__ b_reg,
    float* __restrict__ out, int T) {
  const int jj  = threadIdx.x & 15;   // hidden-lane within row
  const int row = threadIdx.x >> 4;   // 0..15 rows per block
  const int b   = blockIdx.x * 16 + row;

  // Per-lane gathered W_hh so that with row_ror:m (lane j sees h[(j-m)&15])
  // the coefficient is W_hh[out_row, in_col=(j-m)&15].
  float wll[16], wlh[16], whl[16], whh[16];
#pragma unroll
  for (int m = 0; m < 16; ++m) {
    int k = (jj - m) & 15;
    wll[m] = W_hh[jj * HSZ + k];              // out j,    in k
    wlh[m] = W_hh[jj * HSZ + 16 + k];         // out j,    in 16+k
    whl[m] = W_hh[(jj + 16) * HSZ + k];       // out j+16, in k
    whh[m] = W_hh[(jj + 16) * HSZ + 16 + k];  // out j+16, in 16+k
  }
  const float wih_lo = W_ih[jj];
  const float wih_hi = W_ih[jj + 16];
  const float c_lo = b_ih[jj] + b_hh[jj];
  const float c_hi = b_ih[jj + 16] + b_hh[jj + 16];

  float h_lo = h_init[b * HSZ + jj];
  float h_hi = h_init[b * HSZ + jj + 16];

  // x feed: all 16 lanes of a row load the same float4 (HW merges the
  // same-address lanes). 4-deep rotating pipeline = 16-step prefetch
  // distance covering cold-HBM latency (~900 cyc).
  const float4* xv = (const float4*)(x + (size_t)b * (size_t)T);
  const int last = T / 4 - 1;
  float4 x0 = xv[0], x1 = xv[1], x2 = xv[2], x3 = xv[3];

#pragma unroll 1
  for (int t = 0; t < T; t += 16) {
    const int base = t >> 2;
    int i0 = base + 4; i0 = i0 > last ? last : i0;
    int i1 = base + 5; i1 = i1 > last ? last : i1;
    int i2 = base + 6; i2 = i2 > last ? last : i2;
    int i3 = base + 7; i3 = i3 > last ? last : i3;
    float4 n0 = xv[i0];
    RNN_STEP(x0.x); RNN_STEP(x0.y); RNN_STEP(x0.z); RNN_STEP(x0.w);
    float4 n1 = xv[i1];
    RNN_STEP(x1.x); RNN_STEP(x1.y); RNN_STEP(x1.z); RNN_STEP(x1.w);
    float4 n2 = xv[i2];
    RNN_STEP(x2.x); RNN_STEP(x2.y); RNN_STEP(x2.z); RNN_STEP(x2.w);
    float4 n3 = xv[i3];
    RNN_STEP(x3.x); RNN_STEP(x3.y); RNN_STEP(x3.z); RNN_STEP(x3.w);
    x0 = n0; x1 = n1; x2 = n2; x3 = n3;
  }

  // out[b] = sum_j h[j]*W_reg[j] + b_reg  (reduce across the 16-lane row)
  const float wr_lo = W_reg[jj];
  const float wr_hi = W_reg[jj + 16];
  float v = fmaf(h_lo, wr_lo, h_hi * wr_hi);
  v += __shfl_xor(v, 1, 16);
  v += __shfl_xor(v, 2, 16);
  v += __shfl_xor(v, 4, 16);
  v += __shfl_xor(v, 8, 16);
  if (jj == 0) out[b] = v + b_reg[0];
}

extern "C" void kernel_launch(void* const* d_in, const int* in_sizes, int n_in,
                              void* d_out, int out_size, void* d_ws, size_t ws_size,
                              hipStream_t stream) {
  const float* x      = (const float*)d_in[0];
  const float* h_init = (const float*)d_in[1];
  const float* W_ih   = (const float*)d_in[2];
  const float* W_hh   = (const float*)d_in[3];
  const float* b_ih   = (const float*)d_in[4];
  const float* b_hh   = (const float*)d_in[5];
  const float* W_reg  = (const float*)d_in[6];
  const float* b_reg  = (const float*)d_in[7];
  float* out = (float*)d_out;

  const int B = in_sizes[1] / HSZ;          // 4096
  const int T = in_sizes[0] / B;            // 4096
  const int grid = B / 16;                  // 16 batches (rows) per 256-thr block

  rnn_reg_kernel<<<dim3(grid), dim3(256), 0, stream>>>(
      x, h_init, W_ih, W_hh, b_ih, b_hh, W_reg, b_reg, out, T);
}